// Round 5
// baseline (209.909 us; speedup 1.0000x reference)
//
#include <hip/hip_runtime.h>

// Problem constants (from reference)
#define M_PTS   16385     // int(65536*0.25)+1
#define K_NB    16
#define CIN_C   256
#define COUT_C  512
#define LN_EPS  1e-5f

#define OUT_XYZ_ELEMS (M_PTS * 3)                      // 49155
#define OUT_FEAT_OFF  OUT_XYZ_ELEMS
#define OUT_NOFF_IDX  (OUT_XYZ_ELEMS + M_PTS * COUT_C) // 8438275

#define NBLK 256          // 1 block per CU
#define PPB  65           // ceil(16385/256) points per block

typedef __attribute__((ext_vector_type(8))) short bf16x8;   // 8 bf16 = 4 VGPRs
typedef __attribute__((ext_vector_type(4))) float f32x4;    // MFMA 16x16 accum

// A-tile row stride (ushorts): 264 -> 528 B
#define LDS_STRIDE 264

__device__ __forceinline__ ushort f2bf(float f) {
  unsigned u = __float_as_uint(f);
  u += 0x7FFFu + ((u >> 16) & 1u);   // round-to-nearest-even
  return (ushort)(u >> 16);
}

// Barrier WITHOUT the compiler's vmcnt(0) drain: LDS writes must be visible
// (lgkmcnt(0)), but in-flight global prefetch loads may cross the barrier.
__device__ __forceinline__ void block_sync_lds() {
  asm volatile("s_waitcnt lgkmcnt(0)" ::: "memory");
  __builtin_amdgcn_s_barrier();
}

// Opaque register pin: makes the value non-rematerializable so the register
// allocator CANNOT sink the originating load back into the loop (R3/R4 both
// lost B-residency to exactly that heuristic -> 4.3 GB/launch of L2 re-reads).
__device__ __forceinline__ void pin_frag(bf16x8& v) {
  asm volatile("" : "+v"(v));
}

// Prep: lin_w f32->bf16 into ws, swizzled so each wave's persistent 32-col
// B-chunk load is perfectly coalesced (1KB per instruction):
//   Breg[kk][ct][e] at lane (quad*16+lcol) of wave w
//     = lin_w[o = w*32 + ct*16 + lcol][c = kk*32 + quad*8 + e]
//   pos = [w:4][ct:1][kk:3][quad:2][lcol:4][e:3]
// (fragment semantics validated R2-R4). Also: n_xyz gather, n_offset scalar.
__global__ void prep_kernel(const float* __restrict__ lin_w,
                            const float* __restrict__ xyz,
                            const int*   __restrict__ samp_idx,
                            const int*   __restrict__ offset,
                            ushort* __restrict__ lw_sw,
                            float*  __restrict__ out) {
  int tid = blockIdx.x * 256 + threadIdx.x;
  if (tid < COUT_C * CIN_C) {
    int o = tid >> 8;          // 0..511
    int c = tid & 255;         // 0..255
    int pos = ((o >> 5) << 13) | (((o >> 4) & 1) << 12) | ((c >> 5) << 9)
            | (((c >> 3) & 3) << 7) | ((o & 15) << 3) | (c & 7);
    lw_sw[pos] = f2bf(lin_w[tid]);
  }
  if (tid < OUT_XYZ_ELEMS) {
    int p = tid / 3;
    int c = tid - p * 3;
    out[tid] = xyz[(size_t)samp_idx[p] * 3 + c];
  }
  if (tid == 0) out[OUT_NOFF_IDX] = (float)(offset[0] / 4 + 1);
}

// Fused main: block = 1024 threads = 16 waves. Wave w:
//   - owns output cols [w*32, w*32+32), B resident in 64 VGPRs (pinned!)
//   - gathers + LayerNorms neighbor row w (one coalesced 1KB load, 16B/lane)
// Per point: 16 waves write the 16x256 A-tile (double-buffered LDS),
// lgkm-only barrier, 8 ds_read_b128 + 16 MFMA from registers, maxpool, store.
__global__ __launch_bounds__(1024, 4)
void td_main(const float*  __restrict__ feats,
             const float*  __restrict__ norm_w,
             const float*  __restrict__ norm_b,
             const ushort* __restrict__ lw_sw,
             const int*    __restrict__ knn,
             float* __restrict__ out) {
  __shared__ ushort A[2][16 * LDS_STRIDE];   // 2 x 8448 B
  __shared__ int Kidx[PPB * K_NB];           // 4160 B -> total 21056 B

  const int tid  = threadIdx.x;
  const int lane = tid & 63;
  const int w    = tid >> 6;        // wave = neighbor row AND 32-col chunk
  const int quad = lane >> 4;
  const int lcol = lane & 15;

  const int pstart = blockIdx.x * PPB;
  const int npts   = min(pstart + PPB, M_PTS) - pstart;
  if (npts <= 0) return;            // blocks 253..255 exit (before any barrier)

  // Stage this block's knn indices
  for (int i = tid; i < npts * K_NB; i += 1024)
    Kidx[i] = knn[pstart * K_NB + i];

  // Persistent B chunk: Breg[kk][ct], 64 VGPRs, coalesced 1KB loads, PINNED.
  bf16x8 Breg[8][2];
  {
    const ushort* base = lw_sw + (w << 13) + lane * 8;
#pragma unroll
    for (int ct = 0; ct < 2; ++ct)
#pragma unroll
      for (int kk = 0; kk < 8; ++kk) {
        Breg[kk][ct] = *(const bf16x8*)(base + (ct << 12) + (kk << 9));
        pin_frag(Breg[kk][ct]);     // load result now opaque: cannot be sunk
      }
  }

  // LayerNorm weights for this lane's 4 channels
  const float4 nw = ((const float4*)norm_w)[lane];
  const float4 nb = ((const float4*)norm_b)[lane];

  __syncthreads();                  // Kidx visible

  // Prefetch points 0 and 1 (16B/lane each, one coalesced load per wave)
  float4 f0, f1;
  f0 = ((const float4*)(feats + (size_t)Kidx[w] * CIN_C))[lane];
  f1 = (npts > 1)
     ? ((const float4*)(feats + (size_t)Kidx[K_NB + w] * CIN_C))[lane]
     : f0;

  for (int lp = 0; lp < npts; ++lp) {
    // Prefetch point lp+2 (stays in flight across the lgkm-only barriers)
    float4 ft = f1;
    if (lp + 2 < npts)
      ft = ((const float4*)(feats + (size_t)Kidx[(lp + 2) * K_NB + w] * CIN_C))[lane];

    // LayerNorm row w of point lp (stats across the full wave = 256 ch)
    float s1 = (f0.x + f0.y) + (f0.z + f0.w);
    float s2 = f0.x * f0.x + f0.y * f0.y + f0.z * f0.z + f0.w * f0.w;
    s1 += __shfl_xor(s1, 1, 64);  s2 += __shfl_xor(s2, 1, 64);
    s1 += __shfl_xor(s1, 2, 64);  s2 += __shfl_xor(s2, 2, 64);
    s1 += __shfl_xor(s1, 4, 64);  s2 += __shfl_xor(s2, 4, 64);
    s1 += __shfl_xor(s1, 8, 64);  s2 += __shfl_xor(s2, 8, 64);
    s1 += __shfl_xor(s1, 16, 64); s2 += __shfl_xor(s2, 16, 64);
    s1 += __shfl_xor(s1, 32, 64); s2 += __shfl_xor(s2, 32, 64);
    const float mu  = s1 * (1.0f / 256.0f);
    const float var = fmaf(-mu, mu, s2 * (1.0f / 256.0f));
    const float rs  = rsqrtf(var + LN_EPS);

    ushort4 o4;
    o4.x = f2bf(fmaf((f0.x - mu) * rs, nw.x, nb.x));
    o4.y = f2bf(fmaf((f0.y - mu) * rs, nw.y, nb.y));
    o4.z = f2bf(fmaf((f0.z - mu) * rs, nw.z, nb.z));
    o4.w = f2bf(fmaf((f0.w - mu) * rs, nw.w, nb.w));
    *(ushort4*)&A[lp & 1][w * LDS_STRIDE + lane * 4] = o4;   // ds_write_b64

    block_sync_lds();               // A visible; prefetch NOT drained

    // GEMM: A[16x256] x Breg -> 32 cols; D row = quad*4+reg (validated layout)
    f32x4 acc0 = {0.f, 0.f, 0.f, 0.f}, acc1 = {0.f, 0.f, 0.f, 0.f};
    const ushort* arow = &A[lp & 1][lcol * LDS_STRIDE];
#pragma unroll
    for (int kk = 0; kk < 8; ++kk) {
      bf16x8 af = *(const bf16x8*)&arow[kk * 32 + quad * 8];
      acc0 = __builtin_amdgcn_mfma_f32_16x16x32_bf16(af, Breg[kk][0], acc0, 0, 0, 0);
      acc1 = __builtin_amdgcn_mfma_f32_16x16x32_bf16(af, Breg[kk][1], acc1, 0, 0, 0);
    }

    // Maxpool over 16 neighbor rows, store 32 cols
    float* outp = out + OUT_FEAT_OFF + (size_t)(pstart + lp) * COUT_C + w * 32;
    {
      float v = fmaxf(fmaxf(acc0[0], acc0[1]), fmaxf(acc0[2], acc0[3]));
      v = fmaxf(v, __shfl_xor(v, 16, 64));
      v = fmaxf(v, __shfl_xor(v, 32, 64));
      if (quad == 0) outp[lcol] = v;
    }
    {
      float v = fmaxf(fmaxf(acc1[0], acc1[1]), fmaxf(acc1[2], acc1[3]));
      v = fmaxf(v, __shfl_xor(v, 16, 64));
      v = fmaxf(v, __shfl_xor(v, 32, 64));
      if (quad == 0) outp[16 + lcol] = v;
    }
    // A[lp&1] reuse at lp+2 is ordered by the barrier at lp+1.
    f0 = f1; f1 = ft;
  }
}

extern "C" void kernel_launch(void* const* d_in, const int* in_sizes, int n_in,
                              void* d_out, int out_size, void* d_ws, size_t ws_size,
                              hipStream_t stream) {
  const float* xyz      = (const float*)d_in[0];
  const float* feats    = (const float*)d_in[1];
  const float* norm_w   = (const float*)d_in[2];
  const float* norm_b   = (const float*)d_in[3];
  const float* lin_w    = (const float*)d_in[4];
  const int*   samp_idx = (const int*)d_in[5];
  const int*   knn      = (const int*)d_in[6];
  const int*   offset   = (const int*)d_in[7];
  float*  out   = (float*)d_out;
  ushort* lw_sw = (ushort*)d_ws;                    // 512*256*2 = 256 KB

  prep_kernel<<<512, 256, 0, stream>>>(lin_w, xyz, samp_idx, offset, lw_sw, out);

  td_main<<<NBLK, 1024, 0, stream>>>(feats, norm_w, norm_b, lw_sw, knn, out);
}

// Round 6
// 179.563 us; speedup vs baseline: 1.1690x; 1.1690x over previous
//
#include <hip/hip_runtime.h>

// Problem constants (from reference)
#define M_PTS   16385     // int(65536*0.25)+1
#define K_NB    16
#define CIN_C   256
#define COUT_C  512
#define LN_EPS  1e-5f

#define OUT_XYZ_ELEMS (M_PTS * 3)                      // 49155
#define OUT_FEAT_OFF  OUT_XYZ_ELEMS
#define OUT_NOFF_IDX  (OUT_XYZ_ELEMS + M_PTS * COUT_C) // 8438275

#define NBLK 256          // 1 block per CU
#define PPB  65           // ceil(16385/256) points per block

#define B_SCALE 16.0f     // lin_w pre-scale (keeps e4m3 out of subnormals)
#define B_INV   0.0625f

#define AROW_B 272        // A-tile row stride in BYTES (256 fp8 + 16 pad)

typedef __attribute__((ext_vector_type(4))) float f32x4;

// Barrier WITHOUT the compiler's vmcnt(0) drain: LDS writes must be visible
// (lgkmcnt(0)), but in-flight global prefetch loads may cross the barrier.
__device__ __forceinline__ void block_sync_lds() {
  asm volatile("s_waitcnt lgkmcnt(0)" ::: "memory");
  __builtin_amdgcn_s_barrier();
}

// Full-wave (64-lane) float sum on the VALU pipe via DPP — no DS-pipe ops.
// xor1/xor2 (quad_perm), xor4 (row_half_mirror), xor8 (row_mirror) give each
// lane its row-of-16 sum; bcast15 (rows 1,3) and bcast31 (rows 2,3) fold the
// four rows so lane 63 holds the total; readlane broadcasts via SGPR.
__device__ __forceinline__ float wave_sum64(float v) {
  v += __int_as_float(__builtin_amdgcn_update_dpp(0, __float_as_int(v), 0xB1, 0xF, 0xF, false));
  v += __int_as_float(__builtin_amdgcn_update_dpp(0, __float_as_int(v), 0x4E, 0xF, 0xF, false));
  v += __int_as_float(__builtin_amdgcn_update_dpp(0, __float_as_int(v), 0x141, 0xF, 0xF, false));
  v += __int_as_float(__builtin_amdgcn_update_dpp(0, __float_as_int(v), 0x140, 0xF, 0xF, false));
  v += __int_as_float(__builtin_amdgcn_update_dpp(0, __float_as_int(v), 0x142, 0xA, 0xF, false));
  v += __int_as_float(__builtin_amdgcn_update_dpp(0, __float_as_int(v), 0x143, 0xC, 0xF, false));
  return __int_as_float(__builtin_amdgcn_readlane(__float_as_int(v), 63));
}

// LayerNorm the wave's 256-ch row (lane holds ch 4L..4L+3) and pack to 4 fp8.
__device__ __forceinline__ int ln_pack(float4 g, float4 nw, float4 nb) {
  float s1 = (g.x + g.y) + (g.z + g.w);
  float s2 = g.x * g.x + g.y * g.y + g.z * g.z + g.w * g.w;
  float S1 = wave_sum64(s1);
  float S2 = wave_sum64(s2);
  float mu  = S1 * (1.0f / 256.0f);
  float var = fmaf(-mu, mu, S2 * (1.0f / 256.0f));
  float rs  = rsqrtf(var + LN_EPS);
  float a = fmaf((g.x - mu) * rs, nw.x, nb.x);
  float b = fmaf((g.y - mu) * rs, nw.y, nb.y);
  float c = fmaf((g.z - mu) * rs, nw.z, nb.z);
  float d = fmaf((g.w - mu) * rs, nw.w, nb.w);
  int v = __builtin_amdgcn_cvt_pk_fp8_f32(a, b, 0, false);   // bytes 0,1
  v = __builtin_amdgcn_cvt_pk_fp8_f32(c, d, v, true);        // bytes 2,3
  return v;
}

// Prep: lin_w -> fp8(e4m3, x16) into ws, swizzled so each wave's persistent
// 32-col B load is coalesced 8B/lane:
//   Breg[kk][g] at lane (quad*16+lcol) of wave w, byte e
//     = fp8(16 * lin_w[o = w*32 + g*16 + lcol][c = kk*32 + quad*8 + e])
//   pos = w*8192 + g*4096 + kk*512 + (quad*16+lcol)*8 + e
// Also: n_xyz gather and n_offset scalar.
__global__ void prep_kernel(const float* __restrict__ lin_w,
                            const float* __restrict__ xyz,
                            const int*   __restrict__ samp_idx,
                            const int*   __restrict__ offset,
                            unsigned char* __restrict__ lw8,
                            float*  __restrict__ out) {
  int tid = blockIdx.x * 256 + threadIdx.x;
  if (tid < COUT_C * CIN_C) {
    int o = tid >> 8;          // 0..511
    int c = tid & 255;         // 0..255
    int pos = ((o >> 5) << 13) | (((o >> 4) & 1) << 12) | ((c >> 5) << 9)
            | ((((c >> 3) & 3) * 16 + (o & 15)) << 3) | (c & 7);
    int pk = __builtin_amdgcn_cvt_pk_fp8_f32(lin_w[tid] * B_SCALE, 0.0f, 0, false);
    lw8[pos] = (unsigned char)(pk & 0xFF);
  }
  if (tid < OUT_XYZ_ELEMS) {
    int p = tid / 3;
    int c = tid - p * 3;
    out[tid] = xyz[(size_t)samp_idx[p] * 3 + c];
  }
  if (tid == 0) out[OUT_NOFF_IDX] = (float)(offset[0] / 4 + 1);
}

// GEMM one point's 16x256 fp8 A-tile against the wave's 32-col B registers,
// then maxpool over the 16 rows. rowbase = A-row for m=lcol (layout makes the
// (kk=2t, kk=2t+1) frag pair contiguous 16B at t*64 + quad*16).
__device__ __forceinline__ void gemm_pool(const unsigned char* rowbase,
                                          const long Breg[8][2], int quad,
                                          float& v0, float& v1) {
  ulonglong2 q0 = *(const ulonglong2*)(rowbase + 0   + quad * 16);
  ulonglong2 q1 = *(const ulonglong2*)(rowbase + 64  + quad * 16);
  ulonglong2 q2 = *(const ulonglong2*)(rowbase + 128 + quad * 16);
  ulonglong2 q3 = *(const ulonglong2*)(rowbase + 192 + quad * 16);
  f32x4 a0 = {0.f, 0.f, 0.f, 0.f}, a1 = {0.f, 0.f, 0.f, 0.f};
  a0 = __builtin_amdgcn_mfma_f32_16x16x32_fp8_fp8((long)q0.x, Breg[0][0], a0, 0, 0, 0);
  a1 = __builtin_amdgcn_mfma_f32_16x16x32_fp8_fp8((long)q0.x, Breg[0][1], a1, 0, 0, 0);
  a0 = __builtin_amdgcn_mfma_f32_16x16x32_fp8_fp8((long)q0.y, Breg[1][0], a0, 0, 0, 0);
  a1 = __builtin_amdgcn_mfma_f32_16x16x32_fp8_fp8((long)q0.y, Breg[1][1], a1, 0, 0, 0);
  a0 = __builtin_amdgcn_mfma_f32_16x16x32_fp8_fp8((long)q1.x, Breg[2][0], a0, 0, 0, 0);
  a1 = __builtin_amdgcn_mfma_f32_16x16x32_fp8_fp8((long)q1.x, Breg[2][1], a1, 0, 0, 0);
  a0 = __builtin_amdgcn_mfma_f32_16x16x32_fp8_fp8((long)q1.y, Breg[3][0], a0, 0, 0, 0);
  a1 = __builtin_amdgcn_mfma_f32_16x16x32_fp8_fp8((long)q1.y, Breg[3][1], a1, 0, 0, 0);
  a0 = __builtin_amdgcn_mfma_f32_16x16x32_fp8_fp8((long)q2.x, Breg[4][0], a0, 0, 0, 0);
  a1 = __builtin_amdgcn_mfma_f32_16x16x32_fp8_fp8((long)q2.x, Breg[4][1], a1, 0, 0, 0);
  a0 = __builtin_amdgcn_mfma_f32_16x16x32_fp8_fp8((long)q2.y, Breg[5][0], a0, 0, 0, 0);
  a1 = __builtin_amdgcn_mfma_f32_16x16x32_fp8_fp8((long)q2.y, Breg[5][1], a1, 0, 0, 0);
  a0 = __builtin_amdgcn_mfma_f32_16x16x32_fp8_fp8((long)q3.x, Breg[6][0], a0, 0, 0, 0);
  a1 = __builtin_amdgcn_mfma_f32_16x16x32_fp8_fp8((long)q3.x, Breg[6][1], a1, 0, 0, 0);
  a0 = __builtin_amdgcn_mfma_f32_16x16x32_fp8_fp8((long)q3.y, Breg[7][0], a0, 0, 0, 0);
  a1 = __builtin_amdgcn_mfma_f32_16x16x32_fp8_fp8((long)q3.y, Breg[7][1], a1, 0, 0, 0);
  // D layout: col = lane&15, row = quad*4 + reg (validated). Maxpool 16 rows.
  v0 = fmaxf(fmaxf(a0[0], a0[1]), fmaxf(a0[2], a0[3]));
  v0 = fmaxf(v0, __shfl_xor(v0, 16, 64));
  v0 = fmaxf(v0, __shfl_xor(v0, 32, 64));
  v1 = fmaxf(fmaxf(a1[0], a1[1]), fmaxf(a1[2], a1[3]));
  v1 = fmaxf(v1, __shfl_xor(v1, 16, 64));
  v1 = fmaxf(v1, __shfl_xor(v1, 32, 64));
}

// Fused main: block = 1024 threads = 16 waves, 2 points per iteration.
// Wave w: owns output cols [w*32, w*32+32) (B fp8 in 32 VGPRs, pinned),
// gathers + LayerNorms row w of BOTH points (DPP reduce — no DS-pipe ops),
// writes fp8 A rows (w and 16+w) into double-buffered LDS; after an
// lgkm-only barrier, 8 ds_read_b128 + 32 MFMA, maxpool, store 32 cols x 2 pts.
__global__ __launch_bounds__(1024, 4)
void td_main(const float*  __restrict__ feats,
             const float*  __restrict__ norm_w,
             const float*  __restrict__ norm_b,
             const unsigned char* __restrict__ lw8,
             const int*    __restrict__ knn,
             float* __restrict__ out) {
  __shared__ unsigned char A8[2][32 * AROW_B];   // 2 x 8704 B
  __shared__ int Kidx[PPB * K_NB];               // 4160 B -> total 21568 B

  const int tid  = threadIdx.x;
  const int lane = tid & 63;
  const int w    = tid >> 6;        // wave = neighbor row AND 32-col chunk
  const int quad = lane >> 4;
  const int lcol = lane & 15;

  const int pstart = blockIdx.x * PPB;
  const int npts   = min(pstart + PPB, M_PTS) - pstart;
  if (npts <= 0) return;            // blocks 253..255 exit before any barrier

  // Stage this block's knn indices
  for (int i = tid; i < npts * K_NB; i += 1024)
    Kidx[i] = knn[pstart * K_NB + i];

  // Persistent fp8 B chunk: Breg[kk][g], 32 VGPRs, coalesced 8B/lane loads
  long Breg[8][2];
  {
    const unsigned char* base = lw8 + (w << 13) + lane * 8;
#pragma unroll
    for (int g = 0; g < 2; ++g)
#pragma unroll
      for (int kk = 0; kk < 8; ++kk) {
        Breg[kk][g] = *(const long*)(base + (g << 12) + (kk << 9));
        asm volatile("" : "+v"(Breg[kk][g]));   // opaque: cannot be re-sunk
      }
  }

  // LayerNorm weights for this lane's 4 channels
  const float4 nw = ((const float4*)norm_w)[lane];
  const float4 nb = ((const float4*)norm_b)[lane];

  // A-write byte offset within a row: permuted so (kk=2t,kk=2t+1) frag pairs
  // are contiguous: dword for channels 4L..4L+3 lands at
  //   t*64 + q*16 + (kk&1)*8 + e0   (t=L>>4, q=(L>>1)&3, kk&1 = (L>>3)&1)
  const int wdw = ((lane >> 4) << 6) + (((lane >> 1) & 3) << 4)
                + (lane & 8) + ((lane & 1) << 2);

  __syncthreads();                  // Kidx visible (full sync, once)

  // Preload pair 0 (rows w of points 0 and 1), 16B/lane coalesced
  float4 fa = ((const float4*)(feats + (size_t)Kidx[w] * CIN_C))[lane];
  float4 fb = ((const float4*)(feats +
               (size_t)Kidx[min(1, npts - 1) * K_NB + w] * CIN_C))[lane];

  const int nit = (npts + 1) >> 1;
  for (int it = 0; it < nit; ++it) {
    const int pa = 2 * it, pb = 2 * it + 1;

    // Prefetch pair it+1 (crosses the lgkm-only barrier un-drained)
    float4 na = fa, nb2 = fb;
    if (it + 1 < nit) {
      int qa = min(pa + 2, npts - 1), qb = min(pa + 3, npts - 1);
      na  = ((const float4*)(feats + (size_t)Kidx[qa * K_NB + w] * CIN_C))[lane];
      nb2 = ((const float4*)(feats + (size_t)Kidx[qb * K_NB + w] * CIN_C))[lane];
    }

    // LayerNorm + fp8-pack + LDS write: rows w (pt a) and 16+w (pt b)
    unsigned char* Ab = A8[it & 1];
    *(int*)(Ab + w * AROW_B + wdw)        = ln_pack(fa, nw, nb);
    *(int*)(Ab + (16 + w) * AROW_B + wdw) = ln_pack(fb, nw, nb);

    block_sync_lds();               // A visible; prefetch NOT drained

    // GEMM + maxpool, point a then point b
    float v0, v1;
    gemm_pool(Ab + lcol * AROW_B, Breg, quad, v0, v1);
    float* outa = out + OUT_FEAT_OFF + (size_t)(pstart + pa) * COUT_C + w * 32;
    if (quad < 2) outa[quad * 16 + lcol] = (quad ? v1 : v0) * B_INV;

    gemm_pool(Ab + (16 + lcol) * AROW_B, Breg, quad, v0, v1);
    if (pb < npts) {
      float* outb = out + OUT_FEAT_OFF + (size_t)(pstart + pb) * COUT_C + w * 32;
      if (quad < 2) outb[quad * 16 + lcol] = (quad ? v1 : v0) * B_INV;
    }
    // A[it&1] reuse at it+2 is ordered by the barrier at it+1.
    fa = na; fb = nb2;
  }
}

extern "C" void kernel_launch(void* const* d_in, const int* in_sizes, int n_in,
                              void* d_out, int out_size, void* d_ws, size_t ws_size,
                              hipStream_t stream) {
  const float* xyz      = (const float*)d_in[0];
  const float* feats    = (const float*)d_in[1];
  const float* norm_w   = (const float*)d_in[2];
  const float* norm_b   = (const float*)d_in[3];
  const float* lin_w    = (const float*)d_in[4];
  const int*   samp_idx = (const int*)d_in[5];
  const int*   knn      = (const int*)d_in[6];
  const int*   offset   = (const int*)d_in[7];
  float* out = (float*)d_out;
  unsigned char* lw8 = (unsigned char*)d_ws;        // 512*256 = 128 KB fp8

  prep_kernel<<<512, 256, 0, stream>>>(lin_w, xyz, samp_idx, offset, lw8, out);

  td_main<<<NBLK, 1024, 0, stream>>>(feats, norm_w, norm_b, lw8, knn, out);
}